// Round 5
// baseline (962.382 us; speedup 1.0000x reference)
//
#include <hip/hip_runtime.h>
#include <hip/hip_bf16.h>
#include <cstdint>
#include <cstddef>

// Problem constants
#define T_TOK 4096   // BATCH*SEQ
#define DM    1024   // D_MODEL
#define DF    4096   // D_FF
#define NE    8      // N_EXPERTS (TOP_K = 2)

typedef unsigned short u16;
typedef __attribute__((ext_vector_type(8))) short  short8;
typedef __attribute__((ext_vector_type(8))) unsigned short u16x8;
typedef __attribute__((ext_vector_type(4))) float  f32x4;
typedef __attribute__((ext_vector_type(2))) unsigned short u16x2;
typedef __attribute__((ext_vector_type(4))) unsigned short u16x4;

__device__ __forceinline__ u16 f2b(float f) {
  union { float f; uint32_t u; } v; v.f = f;
  uint32_t u = v.u;
  u += 0x7fffu + ((u >> 16) & 1u);   // round-to-nearest-even
  return (u16)(u >> 16);
}
__device__ __forceinline__ float b2f(u16 b) {
  union { uint32_t u; float f; } v; v.u = ((uint32_t)b) << 16; return v.f;
}

// async global->LDS, 16B per lane. LDS dest is WAVE-UNIFORM base; HW adds lane*16.
__device__ __forceinline__ void gload_lds16(const u16* gsrc, u16* lds) {
  __builtin_amdgcn_global_load_lds(
      (const __attribute__((address_space(1))) void*)gsrc,
      (__attribute__((address_space(3))) void*)lds, 16, 0, 0);
}

// counted waits + raw barrier (compiler fences on both sides)
__device__ __forceinline__ void wait_vm8() { asm volatile("s_waitcnt vmcnt(8)" ::: "memory"); }
__device__ __forceinline__ void wait_vm0() { asm volatile("s_waitcnt vmcnt(0)" ::: "memory"); }
__device__ __forceinline__ void barrier_raw() {
  asm volatile("" ::: "memory");
  __builtin_amdgcn_s_barrier();
  asm volatile("" ::: "memory");
}

// ---------------- elementwise fp32 -> bf16 ----------------
__global__ void cvt_x_kernel(const float* __restrict__ in, u16* __restrict__ out, int n4) {
  int i = blockIdx.x * blockDim.x + threadIdx.x;
  if (i >= n4) return;
  f32x4 v = reinterpret_cast<const f32x4*>(in)[i];
  u16x4 o;
  o.x = f2b(v.x); o.y = f2b(v.y); o.z = f2b(v.z); o.w = f2b(v.w);
  reinterpret_cast<u16x4*>(out)[i] = o;
}

// ---------------- transpose + convert, 9 slices (8 experts + shared) ----------------
__global__ void transpose_cvt9(const float* __restrict__ W, const float* __restrict__ Wshared,
                               u16* __restrict__ dstW, u16* __restrict__ dstWs,
                               int R, int C) {
  __shared__ float tile[64][65];
  int z = blockIdx.z;
  const float* src; u16* dst;
  if (z < NE) { src = W + (size_t)z * R * C; dst = dstW + (size_t)z * R * C; }
  else        { src = Wshared;               dst = dstWs; }
  int c0 = blockIdx.x * 64, r0 = blockIdx.y * 64;
  int tid = threadIdx.x;              // 256 threads
  int tx = tid & 63, ty = tid >> 6;
  for (int i = ty; i < 64; i += 4)
    tile[i][tx] = src[(size_t)(r0 + i) * C + c0 + tx];
  __syncthreads();
  int p = tid & 31, iy = tid >> 5;
  for (int i = iy; i < 64; i += 8) {
    u16x2 v;
    v.x = f2b(tile[2 * p][i]);
    v.y = f2b(tile[2 * p + 1][i]);
    *reinterpret_cast<u16x2*>(&dst[(size_t)(c0 + i) * R + r0 + 2 * p]) = v;
  }
}

// ---------------- gating: fp32 logits, top-2, softmax, counts ----------------
__global__ void gating_kernel(const float* __restrict__ x, const float* __restrict__ Wg,
                              int* __restrict__ counts, int* __restrict__ top_e,
                              float* __restrict__ top_w) {
  int t = (blockIdx.x * blockDim.x + threadIdx.x) >> 6;
  int lane = threadIdx.x & 63;
  if (t >= T_TOK) return;
  const float* xr = x + (size_t)t * DM;
  float acc[NE];
#pragma unroll
  for (int e = 0; e < NE; ++e) acc[e] = 0.f;
  for (int d = lane; d < DM; d += 64) {
    float xv = xr[d];
    const float* wr = Wg + d * NE;
#pragma unroll
    for (int e = 0; e < NE; ++e) acc[e] += xv * wr[e];
  }
#pragma unroll
  for (int off = 32; off > 0; off >>= 1) {
#pragma unroll
    for (int e = 0; e < NE; ++e) acc[e] += __shfl_down(acc[e], off);
  }
  if (lane == 0) {
    int e0 = 0; float v0 = acc[0];
#pragma unroll
    for (int e = 1; e < NE; ++e) if (acc[e] > v0) { v0 = acc[e]; e0 = e; }
    int e1 = -1; float v1 = -3.4e38f;
#pragma unroll
    for (int e = 0; e < NE; ++e) if (e != e0 && acc[e] > v1) { v1 = acc[e]; e1 = e; }
    float s = expf(v1 - v0);              // v1 <= v0, stable
    float inv = 1.f / (1.f + s);
    top_e[t * 2] = e0; top_e[t * 2 + 1] = e1;
    top_w[t * 2] = inv; top_w[t * 2 + 1] = s * inv;
    atomicAdd(&counts[e0], 1);
    atomicAdd(&counts[e1], 1);
  }
}

__global__ void offsets_kernel(const int* __restrict__ counts, int* __restrict__ offsets,
                               int* __restrict__ cursor) {
  if (threadIdx.x == 0) {
    int s = 0;
    for (int e = 0; e < NE; ++e) { offsets[e] = s; s += counts[e]; }
    offsets[NE] = s;
  }
  if (threadIdx.x < NE) cursor[threadIdx.x] = 0;
}

__global__ void scatter_kernel(const int* __restrict__ top_e,
                               const int* __restrict__ offsets, int* __restrict__ cursor,
                               int* __restrict__ pair_token, int* __restrict__ slot_of) {
  int t = blockIdx.x * blockDim.x + threadIdx.x;
  if (t >= T_TOK) return;
#pragma unroll
  for (int k = 0; k < 2; ++k) {
    int e = top_e[t * 2 + k];
    int slot = atomicAdd(&cursor[e], 1);
    int s = offsets[e] + slot;
    pair_token[s] = t;
    slot_of[t * 2 + k] = s;
  }
}

// ---------------- gather expert A-rows into grouped order (fp32 -> bf16) ----------------
__global__ void gather_x(const float* __restrict__ x, const int* __restrict__ pair_token,
                         u16* __restrict__ Xg) {
  int s = blockIdx.x;                 // slot 0..2*T_TOK-1
  int t = pair_token[s];
  const f32x4* src = reinterpret_cast<const f32x4*>(x + (size_t)t * DM);
  u16x4* dst = reinterpret_cast<u16x4*>(Xg + (size_t)s * DM);
  int i = threadIdx.x;                // 256 threads, DM/4 = 256
  f32x4 v = src[i];
  u16x4 o;
  o.x = f2b(v.x); o.y = f2b(v.y); o.z = f2b(v.z); o.w = f2b(v.w);
  dst[i] = o;
}

// ---------------- grouped FFN GEMM: 256x256, BK=64, 8 waves ----------------
// Counted-vmcnt 2-tile-deep pipeline: STAGE t+2 after the read-done barrier;
// main loop waits vmcnt(8) (oldest 8 = current tile), NEVER vmcnt(0).
// PASS 1: H[base+r] = relu(A[r] @ W1T^T + b1)   A = Xg (experts) / Xb (shared), K=1024
// PASS 2: Ytmp[base+r] = H[base+r] @ W2T^T      K=4096; bias+gate applied in combine
// LDS linear; bank conflicts killed by chunk-XOR on BOTH global source and ds_read.
template <int PASS>
__global__ __launch_bounds__(512, 2)
void ffn_gemm(const u16* __restrict__ Xb, const u16* __restrict__ Xg,
              u16* __restrict__ H,
              const u16* __restrict__ WT, const u16* __restrict__ WsT,
              const float* __restrict__ bias_e, const float* __restrict__ bias_s,
              const int* __restrict__ counts, const int* __restrict__ offsets,
              u16* __restrict__ Ytmp) {
  constexpr int K  = (PASS == 1) ? DM : DF;
  constexpr int N  = (PASS == 1) ? DF : DM;
  constexpr int NT = K / 64;

  // T1 XCD swizzle, y (row-block) innermost: one XCD chunk reuses one B-panel
  const int gx = gridDim.x, gy = gridDim.y;
  const int f = (blockIdx.z * gx + blockIdx.x) * gy + blockIdx.y;
  const int cpx = (gx * gy * gridDim.z) >> 3;     // nwg % 8 == 0 by construction
  const int swz = (f & 7) * cpx + (f >> 3);
  const int by = swz % gy;
  const int bx = (swz / gy) % gx;
  const int e  = swz / (gy * gx);

  int cnt, base;
  if (e < NE) { cnt = counts[e]; base = offsets[e]; }
  else        { cnt = T_TOK;     base = 2 * T_TOK; }   // shared rows at slot 8192..
  const int row0 = by * 256;
  if (row0 >= cnt) return;
  const int col0 = bx * 256;

  __shared__ alignas(16) u16 As0[256 * 64];
  __shared__ alignas(16) u16 Bs0[256 * 64];
  __shared__ alignas(16) u16 As1[256 * 64];
  __shared__ alignas(16) u16 Bs1[256 * 64];

  const u16* Ap;
  if (PASS == 1) Ap = (e < NE) ? (Xg + (size_t)base * DM) : Xb;
  else           Ap = H + (size_t)base * DF;
  const u16* Bp = (e < NE) ? (WT + (size_t)e * (size_t)K * N) : WsT;  // [N][K]
  const float* bias = (e < NE) ? (bias_e + (size_t)e * N) : bias_s;

  const int tid = threadIdx.x;
  const int wv = tid >> 6, lane = tid & 63;
  // staging: call j covers rows j*64 + (wv*8 + lane>>3), 16B chunk = lane&7 (XOR-swz)
  const int srow = wv * 8 + (lane >> 3);
  const int schk = lane & 7;
  const u16* a_ptr[4];
  const u16* b_ptr[4];
#pragma unroll
  for (int j = 0; j < 4; ++j) {
    int r = j * 64 + srow;
    int cs = (schk ^ (r & 7)) * 8;          // pre-swizzled global column (elems)
    int ar = row0 + r; if (ar >= cnt) ar = cnt - 1;   // clamp; epilogue masks
    a_ptr[j] = Ap + (size_t)ar * K + cs;    // A leading dim == K for both passes
    b_ptr[j] = Bp + (size_t)(col0 + r) * K + cs;
  }
  const int ldso = wv * 512;     // wave-uniform LDS elem offset within an 8KB call

  auto STAGE = [&](u16* Abuf, u16* Bbuf, int t) {
    const int ko = t * 64;
#pragma unroll
    for (int j = 0; j < 4; ++j) gload_lds16(a_ptr[j] + ko, Abuf + j * 4096 + ldso);
#pragma unroll
    for (int j = 0; j < 4; ++j) gload_lds16(b_ptr[j] + ko, Bbuf + j * 4096 + ldso);
  };

  const int wr = wv >> 2, wc = wv & 3;   // 2 x 4 wave grid; per-wave output 128x64
  const int q = lane >> 4, r16 = lane & 15, r7 = r16 & 7;
  const int xk0 = (q ^ r7) * 8;          // ks=0: logical chunk q   -> phys
  const int xk1 = ((4 + q) ^ r7) * 8;    // ks=1: logical chunk 4+q -> phys

  f32x4 acc[8][4];
#pragma unroll
  for (int i = 0; i < 8; ++i)
#pragma unroll
    for (int j = 0; j < 4; ++j) acc[i][j] = (f32x4)0.f;

  auto COMPUTE = [&](const u16* Abuf, const u16* Bbuf) {
#pragma unroll
    for (int ks = 0; ks < 2; ++ks) {
      const int xk = ks ? xk1 : xk0;
      short8 af[8], bf[4];
#pragma unroll
      for (int mt = 0; mt < 8; ++mt)
        af[mt] = *reinterpret_cast<const short8*>(&Abuf[(wr * 128 + mt * 16 + r16) * 64 + xk]);
#pragma unroll
      for (int nt = 0; nt < 4; ++nt)
        bf[nt] = *reinterpret_cast<const short8*>(&Bbuf[(wc * 64 + nt * 16 + r16) * 64 + xk]);
      __builtin_amdgcn_s_setprio(1);
#pragma unroll
      for (int mt = 0; mt < 8; ++mt)
#pragma unroll
        for (int nt = 0; nt < 4; ++nt)
          acc[mt][nt] = __builtin_amdgcn_mfma_f32_16x16x32_bf16(af[mt], bf[nt], acc[mt][nt], 0, 0, 0);
      __builtin_amdgcn_s_setprio(0);
    }
  };

  // ---- counted-vmcnt pipeline, 2 tiles deep ----
  u16 *Ac = As0, *Bc = Bs0, *An = As1, *Bn = Bs1;
  STAGE(Ac, Bc, 0);
  STAGE(An, Bn, 1);              // 16 loads/wave in flight
#pragma unroll 1
  for (int t = 0; t < NT - 1; ++t) {
    wait_vm8();                  // my oldest 8 (tile t) have landed
    barrier_raw();               // everyone's tile-t loads have landed
    COMPUTE(Ac, Bc);
    barrier_raw();               // all waves done READING current buffer
    if (t + 2 < NT) STAGE(Ac, Bc, t + 2);   // refill just-freed buffer
    u16* tp;
    tp = Ac; Ac = An; An = tp;
    tp = Bc; Bc = Bn; Bn = tp;
  }
  wait_vm0();                    // last tile (8 outstanding)
  barrier_raw();
  COMPUTE(Ac, Bc);

  // epilogue: C/D layout col=lane&15, row=(lane>>4)*4+reg  [verified m89/m91]
#pragma unroll
  for (int mt = 0; mt < 8; ++mt) {
    int rl = wr * 128 + mt * 16 + q * 4;
#pragma unroll
    for (int nt = 0; nt < 4; ++nt) {
      int col = col0 + wc * 64 + nt * 16 + r16;
      float bcol = (PASS == 1) ? bias[col] : 0.f;
#pragma unroll
      for (int v = 0; v < 4; ++v) {
        int r = rl + v;
        if (row0 + r >= cnt) continue;
        float val = acc[mt][nt][v] + bcol;
        if (PASS == 1) {
          val = fmaxf(val, 0.f);
          H[(size_t)(base + row0 + r) * DF + col] = f2b(val);
        } else {
          Ytmp[(size_t)(base + row0 + r) * DM + col] = f2b(val);
        }
      }
    }
  }
}

// ---------------- combine: out[t] = w0*(Y[s0]+b2[e0]) + w1*(Y[s1]+b2[e1]) + Y[sh]+bs2 ----
__global__ void combine_kernel(const u16* __restrict__ Ytmp, const int* __restrict__ slot_of,
                               const int* __restrict__ top_e, const float* __restrict__ top_w,
                               const float* __restrict__ b2, const float* __restrict__ bs2,
                               float* __restrict__ out) {
  int gid = blockIdx.x * blockDim.x + threadIdx.x;   // one per (token, 8-col group)
  int t = gid >> 7;
  int c8 = (gid & 127) * 8;
  if (t >= T_TOK) return;
  int s0 = slot_of[t * 2], s1 = slot_of[t * 2 + 1];
  int e0 = top_e[t * 2],  e1 = top_e[t * 2 + 1];
  float w0 = top_w[t * 2], w1 = top_w[t * 2 + 1];
  u16x8 y0 = *reinterpret_cast<const u16x8*>(Ytmp + (size_t)s0 * DM + c8);
  u16x8 y1 = *reinterpret_cast<const u16x8*>(Ytmp + (size_t)s1 * DM + c8);
  u16x8 ys = *reinterpret_cast<const u16x8*>(Ytmp + (size_t)(2 * T_TOK + t) * DM + c8);
  const float* b0 = b2 + (size_t)e0 * DM + c8;
  const float* b1p = b2 + (size_t)e1 * DM + c8;
  const float* bs = bs2 + c8;
  float r[8];
#pragma unroll
  for (int v = 0; v < 8; ++v)
    r[v] = w0 * (b2f(y0[v]) + b0[v]) + w1 * (b2f(y1[v]) + b1p[v]) + (b2f(ys[v]) + bs[v]);
  float* o = out + (size_t)t * DM + c8;
#pragma unroll
  for (int v = 0; v < 8; ++v) o[v] = r[v];
}

extern "C" void kernel_launch(void* const* d_in, const int* in_sizes, int n_in,
                              void* d_out, int out_size, void* d_ws, size_t ws_size,
                              hipStream_t stream) {
  const float* x   = (const float*)d_in[0];
  const float* Wg  = (const float*)d_in[1];
  const float* W1  = (const float*)d_in[2];
  const float* b1  = (const float*)d_in[3];
  const float* W2  = (const float*)d_in[4];
  const float* b2  = (const float*)d_in[5];
  const float* Ws1 = (const float*)d_in[6];
  const float* bs1 = (const float*)d_in[7];
  const float* Ws2 = (const float*)d_in[8];
  const float* bs2 = (const float*)d_in[9];

  // workspace layout
  char* ws = (char*)d_ws;
  size_t off = 0;
  auto alloc = [&](size_t bytes) -> char* {
    char* p = ws + off;
    off = (off + bytes + 255) & ~(size_t)255;
    return p;
  };
  int*   counts     = (int*)  alloc(NE * 4);
  int*   offsets    = (int*)  alloc((NE + 1) * 4);
  int*   cursor     = (int*)  alloc(NE * 4);
  int*   top_e      = (int*)  alloc((size_t)T_TOK * 2 * 4);
  float* top_w      = (float*)alloc((size_t)T_TOK * 2 * 4);
  int*   pair_token = (int*)  alloc((size_t)T_TOK * 2 * 4);
  int*   slot_of    = (int*)  alloc((size_t)T_TOK * 2 * 4);
  u16*   Xb   = (u16*)alloc((size_t)T_TOK * DM * 2);
  u16*   Xg   = (u16*)alloc((size_t)2 * T_TOK * DM * 2);  // grouped expert A-rows
  u16*   W1T  = (u16*)alloc((size_t)NE * DM * DF * 2);    // [e][DF][DM]; dead after pass1
  u16*   W2T  = (u16*)alloc((size_t)NE * DM * DF * 2);    // [e][DM][DF]
  u16*   Ws1T = (u16*)alloc((size_t)DM * DF * 2);         // [DF][DM]
  u16*   Ws2T = (u16*)alloc((size_t)DM * DF * 2);         // [DM][DF]
  u16*   H    = (u16*)alloc((size_t)3 * T_TOK * DF * 2);  // 8192 pair rows + 4096 shared
  u16*   Ytmp = W1T;   // overlay: W1T fully rewritten every launch before pass1
  (void)ws_size; (void)in_sizes; (void)n_in;

  hipMemsetAsync(counts, 0, NE * 4, stream);

  cvt_x_kernel<<<(T_TOK * DM / 4 + 255) / 256, 256, 0, stream>>>(x, Xb, T_TOK * DM / 4);
  transpose_cvt9<<<dim3(DF / 64, DM / 64, NE + 1), 256, 0, stream>>>(W1, Ws1, W1T, Ws1T, DM, DF);
  transpose_cvt9<<<dim3(DM / 64, DF / 64, NE + 1), 256, 0, stream>>>(W2, Ws2, W2T, Ws2T, DF, DM);

  gating_kernel<<<T_TOK / 4, 256, 0, stream>>>(x, Wg, counts, top_e, top_w);
  offsets_kernel<<<1, 64, 0, stream>>>(counts, offsets, cursor);
  scatter_kernel<<<T_TOK / 256, 256, 0, stream>>>(top_e, offsets, cursor, pair_token, slot_of);
  gather_x<<<2 * T_TOK, 256, 0, stream>>>(x, pair_token, Xg);

  // pass1: grid (16, 16, 9) = 2304 blocks (%8==0)
  ffn_gemm<1><<<dim3(DF / 256, T_TOK / 256, NE + 1), 512, 0, stream>>>(
      Xb, Xg, H, W1T, Ws1T, b1, bs1, counts, offsets, Ytmp);
  // pass2: grid (4, 16, 9) = 576 blocks (%8==0)
  ffn_gemm<2><<<dim3(DM / 256, T_TOK / 256, NE + 1), 512, 0, stream>>>(
      Xb, Xg, H, W2T, Ws2T, b2, bs2, counts, offsets, Ytmp);

  combine_kernel<<<(T_TOK * 128) / 256, 256, 0, stream>>>(
      Ytmp, slot_of, top_e, top_w, b2, bs2, (float*)d_out);
}

// Round 6
// 553.349 us; speedup vs baseline: 1.7392x; 1.7392x over previous
//
#include <hip/hip_runtime.h>
#include <hip/hip_bf16.h>
#include <cstdint>
#include <cstddef>

// Problem constants
#define T_TOK 4096   // BATCH*SEQ
#define DM    1024   // D_MODEL
#define DF    4096   // D_FF
#define NE    8      // N_EXPERTS (TOP_K = 2)
#define MAXRB 104    // max 128-row blocks: padded experts (<=71) + shared (32)

typedef unsigned short u16;
typedef __attribute__((ext_vector_type(8))) short  short8;
typedef __attribute__((ext_vector_type(8))) unsigned short u16x8;
typedef __attribute__((ext_vector_type(4))) float  f32x4;
typedef __attribute__((ext_vector_type(2))) unsigned short u16x2;
typedef __attribute__((ext_vector_type(4))) unsigned short u16x4;

__device__ __forceinline__ u16 f2b(float f) {
  union { float f; uint32_t u; } v; v.f = f;
  uint32_t u = v.u;
  u += 0x7fffu + ((u >> 16) & 1u);   // round-to-nearest-even
  return (u16)(u >> 16);
}
__device__ __forceinline__ float b2f(u16 b) {
  union { uint32_t u; float f; } v; v.u = ((uint32_t)b) << 16; return v.f;
}

// async global->LDS, 16B per lane. LDS dest is WAVE-UNIFORM base; HW adds lane*16.
__device__ __forceinline__ void gload_lds16(const u16* gsrc, u16* lds) {
  __builtin_amdgcn_global_load_lds(
      (const __attribute__((address_space(1))) void*)gsrc,
      (__attribute__((address_space(3))) void*)lds, 16, 0, 0);
}

// ---------------- elementwise fp32 -> bf16 ----------------
__global__ void cvt_x_kernel(const float* __restrict__ in, u16* __restrict__ out, int n4) {
  int i = blockIdx.x * blockDim.x + threadIdx.x;
  if (i >= n4) return;
  f32x4 v = reinterpret_cast<const f32x4*>(in)[i];
  u16x4 o;
  o.x = f2b(v.x); o.y = f2b(v.y); o.z = f2b(v.z); o.w = f2b(v.w);
  reinterpret_cast<u16x4*>(out)[i] = o;
}

// ---------------- transpose + convert, 9 slices (8 experts + shared) ----------------
__global__ void transpose_cvt9(const float* __restrict__ W, const float* __restrict__ Wshared,
                               u16* __restrict__ dstW, u16* __restrict__ dstWs,
                               int R, int C) {
  __shared__ float tile[64][65];
  int z = blockIdx.z;
  const float* src; u16* dst;
  if (z < NE) { src = W + (size_t)z * R * C; dst = dstW + (size_t)z * R * C; }
  else        { src = Wshared;               dst = dstWs; }
  int c0 = blockIdx.x * 64, r0 = blockIdx.y * 64;
  int tid = threadIdx.x;              // 256 threads
  int tx = tid & 63, ty = tid >> 6;
  for (int i = ty; i < 64; i += 4)
    tile[i][tx] = src[(size_t)(r0 + i) * C + c0 + tx];
  __syncthreads();
  int p = tid & 31, iy = tid >> 5;
  for (int i = iy; i < 64; i += 8) {
    u16x2 v;
    v.x = f2b(tile[2 * p][i]);
    v.y = f2b(tile[2 * p + 1][i]);
    *reinterpret_cast<u16x2*>(&dst[(size_t)(c0 + i) * R + r0 + 2 * p]) = v;
  }
}

// ---------------- gating: fp32 logits, top-2, softmax, counts ----------------
__global__ void gating_kernel(const float* __restrict__ x, const float* __restrict__ Wg,
                              int* __restrict__ counts, int* __restrict__ top_e,
                              float* __restrict__ top_w) {
  int t = (blockIdx.x * blockDim.x + threadIdx.x) >> 6;
  int lane = threadIdx.x & 63;
  if (t >= T_TOK) return;
  const float* xr = x + (size_t)t * DM;
  float acc[NE];
#pragma unroll
  for (int e = 0; e < NE; ++e) acc[e] = 0.f;
  for (int d = lane; d < DM; d += 64) {
    float xv = xr[d];
    const float* wr = Wg + d * NE;
#pragma unroll
    for (int e = 0; e < NE; ++e) acc[e] += xv * wr[e];
  }
#pragma unroll
  for (int off = 32; off > 0; off >>= 1) {
#pragma unroll
    for (int e = 0; e < NE; ++e) acc[e] += __shfl_down(acc[e], off);
  }
  if (lane == 0) {
    int e0 = 0; float v0 = acc[0];
#pragma unroll
    for (int e = 1; e < NE; ++e) if (acc[e] > v0) { v0 = acc[e]; e0 = e; }
    int e1 = -1; float v1 = -3.4e38f;
#pragma unroll
    for (int e = 0; e < NE; ++e) if (e != e0 && acc[e] > v1) { v1 = acc[e]; e1 = e; }
    float s = expf(v1 - v0);              // v1 <= v0, stable
    float inv = 1.f / (1.f + s);
    top_e[t * 2] = e0; top_e[t * 2 + 1] = e1;
    top_w[t * 2] = inv; top_w[t * 2 + 1] = s * inv;
    atomicAdd(&counts[e0], 1);
    atomicAdd(&counts[e1], 1);
  }
}

// pad_off[e] = 128-aligned start of expert e's slot range; [NE]=shared base; [NE+1]=Mpad
__global__ void offsets_kernel(const int* __restrict__ counts, int* __restrict__ pad_off,
                               int* __restrict__ cursor) {
  if (threadIdx.x == 0) {
    int s = 0;
    for (int e = 0; e < NE; ++e) {
      pad_off[e] = s;
      s += (counts[e] + 127) & ~127;
    }
    pad_off[NE] = s;               // shared-expert base row
    pad_off[NE + 1] = s + T_TOK;   // total padded rows (multiple of 128)
  }
  if (threadIdx.x < NE) cursor[threadIdx.x] = 0;
}

__global__ void scatter_kernel(const int* __restrict__ top_e,
                               const int* __restrict__ pad_off, int* __restrict__ cursor,
                               int* __restrict__ slot_of) {
  int t = blockIdx.x * blockDim.x + threadIdx.x;
  if (t >= T_TOK) return;
#pragma unroll
  for (int k = 0; k < 2; ++k) {
    int e = top_e[t * 2 + k];
    int slot = pad_off[e] + atomicAdd(&cursor[e], 1);
    slot_of[t * 2 + k] = slot;
  }
}

// ---------------- gather expert A-rows into padded grouped order (fp32 -> bf16) -------
// one block per (token,k) pair; slot from slot_of. Padded slots stay garbage (isolated:
// they feed only padded H/Ytmp rows, which combine never reads).
__global__ void gather_x(const float* __restrict__ x, const int* __restrict__ slot_of,
                         u16* __restrict__ Xg) {
  int p = blockIdx.x;                 // 0..2*T_TOK-1
  int t = p >> 1;
  int slot = slot_of[t * 2 + (p & 1)];
  const f32x4* src = reinterpret_cast<const f32x4*>(x + (size_t)t * DM);
  u16x4* dst = reinterpret_cast<u16x4*>(Xg + (size_t)slot * DM);
  int i = threadIdx.x;                // 256 threads, DM/4 = 256
  f32x4 v = src[i];
  u16x4 o;
  o.x = f2b(v.x); o.y = f2b(v.y); o.z = f2b(v.z); o.w = f2b(v.w);
  dst[i] = o;
}

// ---------------- grouped FFN GEMM: m97 structure, 128x128 tile, 4 waves -------------
// Row-space is densely padded: every block below Mpad does full work (no masking, no
// indirection). 32KB LDS single-buffer -> 4 blocks/CU; TLP hides load latency (m114).
// PASS 1: H[row] = relu(A[row] @ W1T^T + b1)   A = Xg (experts) / Xb (shared), K=1024
// PASS 2: Ytmp[row] = H[row] @ W2T^T           K=4096; bias+gate applied in combine
// LDS linear (gload_lds); conflicts killed by chunk-XOR on BOTH source and ds_read.
template <int PASS>
__global__ __launch_bounds__(256, 4)
void ffn_gemm(const u16* __restrict__ Xb, const u16* __restrict__ Xg,
              u16* __restrict__ H,
              const u16* __restrict__ WT, const u16* __restrict__ WsT,
              const float* __restrict__ bias_e, const float* __restrict__ bias_s,
              const int* __restrict__ pad_off, u16* __restrict__ Ytmp) {
  constexpr int K    = (PASS == 1) ? DM : DF;
  constexpr int N    = (PASS == 1) ? DF : DM;
  constexpr int NCOL = N / 128;
  constexpr int NWG  = NCOL * MAXRB;

  // T1 XCD swizzle; row-block innermost within an XCD chunk
  const int f   = blockIdx.x;
  const int swz = (f & 7) * (NWG >> 3) + (f >> 3);
  const int rb  = swz % MAXRB;
  const int col0 = (swz / MAXRB) * 128;

  const int shbase = pad_off[NE];
  const int mtot   = pad_off[NE + 1];
  const int grow0  = rb * 128;            // global padded row (tile never spans experts)
  if (grow0 >= mtot) return;

  int e = NE;                             // shared unless below shbase
  if (grow0 < shbase) {
    e = 0;
#pragma unroll
    for (int i = 1; i < NE; ++i) if (grow0 >= pad_off[i]) e = i;
  }

  const u16* Ap;
  if (PASS == 1) Ap = (e < NE) ? (Xg + (size_t)grow0 * DM)
                               : (Xb + (size_t)(grow0 - shbase) * DM);
  else           Ap = H + (size_t)grow0 * DF;
  const u16* Bp = (e < NE) ? (WT + (size_t)e * (size_t)K * N) : WsT;   // [N][K]
  const float* bias = (e < NE) ? (bias_e + (size_t)e * N) : bias_s;

  __shared__ alignas(16) u16 As[128 * 64];
  __shared__ alignas(16) u16 Bs[128 * 64];

  const int tid = threadIdx.x;
  const int wv = tid >> 6, lane = tid & 63;
  // staging: call j covers rows j*32 + (wv*8 + lane>>3); 16B chunk = lane&7 (XOR-swz)
  const int srow = wv * 8 + (lane >> 3);
  const int schk = lane & 7;
  const u16* a_ptr[4];
  const u16* b_ptr[4];
#pragma unroll
  for (int j = 0; j < 4; ++j) {
    int r = j * 32 + srow;
    int cs = (schk ^ (r & 7)) * 8;        // pre-swizzled global column (elems)
    a_ptr[j] = Ap + (size_t)r * K + cs;
    b_ptr[j] = Bp + (size_t)(col0 + r) * K + cs;
  }
  const int ldso = wv * 512;              // wave-uniform LDS elem offset per 4KB call

  const int wr = wv >> 1, wc = wv & 1;    // 2x2 wave grid; per-wave output 64x64
  const int q = lane >> 4, r16 = lane & 15, r7 = r16 & 7;
  const int xk0 = (q ^ r7) * 8;           // ks=0: logical chunk q   -> phys
  const int xk1 = ((4 + q) ^ r7) * 8;     // ks=1: logical chunk 4+q -> phys

  f32x4 acc[4][4];
#pragma unroll
  for (int i = 0; i < 4; ++i)
#pragma unroll
    for (int j = 0; j < 4; ++j) acc[i][j] = (f32x4)0.f;

#pragma unroll 1
  for (int k0 = 0; k0 < K; k0 += 64) {
    __syncthreads();                      // prev iter's LDS reads done
#pragma unroll
    for (int j = 0; j < 4; ++j) gload_lds16(a_ptr[j] + k0, As + j * 2048 + ldso);
#pragma unroll
    for (int j = 0; j < 4; ++j) gload_lds16(b_ptr[j] + k0, Bs + j * 2048 + ldso);
    __syncthreads();                      // vmcnt(0) drain at barrier: tile ready
#pragma unroll
    for (int ks = 0; ks < 2; ++ks) {
      const int xk = ks ? xk1 : xk0;
      short8 af[4], bf[4];
#pragma unroll
      for (int mt = 0; mt < 4; ++mt)
        af[mt] = *reinterpret_cast<const short8*>(&As[(wr * 64 + mt * 16 + r16) * 64 + xk]);
#pragma unroll
      for (int nt = 0; nt < 4; ++nt)
        bf[nt] = *reinterpret_cast<const short8*>(&Bs[(wc * 64 + nt * 16 + r16) * 64 + xk]);
#pragma unroll
      for (int mt = 0; mt < 4; ++mt)
#pragma unroll
        for (int nt = 0; nt < 4; ++nt)
          acc[mt][nt] = __builtin_amdgcn_mfma_f32_16x16x32_bf16(af[mt], bf[nt], acc[mt][nt], 0, 0, 0);
    }
  }

  // epilogue: C/D layout col=lane&15, row=(lane>>4)*4+reg  [verified m89/m91]
#pragma unroll
  for (int mt = 0; mt < 4; ++mt) {
    int rl = wr * 64 + mt * 16 + q * 4;
#pragma unroll
    for (int nt = 0; nt < 4; ++nt) {
      int col = col0 + wc * 64 + nt * 16 + r16;
      float bcol = (PASS == 1) ? bias[col] : 0.f;
#pragma unroll
      for (int v = 0; v < 4; ++v) {
        int r = rl + v;
        float val = acc[mt][nt][v] + bcol;
        if (PASS == 1) {
          val = fmaxf(val, 0.f);
          H[(size_t)(grow0 + r) * DF + col] = f2b(val);
        } else {
          Ytmp[(size_t)(grow0 + r) * DM + col] = f2b(val);
        }
      }
    }
  }
}

// ---------------- combine: out[t] = w0*(Y[s0]+b2[e0]) + w1*(Y[s1]+b2[e1]) + Y[sh]+bs2 ----
__global__ void combine_kernel(const u16* __restrict__ Ytmp, const int* __restrict__ slot_of,
                               const int* __restrict__ top_e, const float* __restrict__ top_w,
                               const float* __restrict__ b2, const float* __restrict__ bs2,
                               const int* __restrict__ pad_off, float* __restrict__ out) {
  int gid = blockIdx.x * blockDim.x + threadIdx.x;   // one per (token, 8-col group)
  int t = gid >> 7;
  int c8 = (gid & 127) * 8;
  if (t >= T_TOK) return;
  int shbase = pad_off[NE];
  int s0 = slot_of[t * 2], s1 = slot_of[t * 2 + 1];
  int e0 = top_e[t * 2],  e1 = top_e[t * 2 + 1];
  float w0 = top_w[t * 2], w1 = top_w[t * 2 + 1];
  u16x8 y0 = *reinterpret_cast<const u16x8*>(Ytmp + (size_t)s0 * DM + c8);
  u16x8 y1 = *reinterpret_cast<const u16x8*>(Ytmp + (size_t)s1 * DM + c8);
  u16x8 ys = *reinterpret_cast<const u16x8*>(Ytmp + (size_t)(shbase + t) * DM + c8);
  const float* b0 = b2 + (size_t)e0 * DM + c8;
  const float* b1p = b2 + (size_t)e1 * DM + c8;
  const float* bs = bs2 + c8;
  float r[8];
#pragma unroll
  for (int v = 0; v < 8; ++v)
    r[v] = w0 * (b2f(y0[v]) + b0[v]) + w1 * (b2f(y1[v]) + b1p[v]) + (b2f(ys[v]) + bs[v]);
  float* o = out + (size_t)t * DM + c8;
#pragma unroll
  for (int v = 0; v < 8; ++v) o[v] = r[v];
}

extern "C" void kernel_launch(void* const* d_in, const int* in_sizes, int n_in,
                              void* d_out, int out_size, void* d_ws, size_t ws_size,
                              hipStream_t stream) {
  const float* x   = (const float*)d_in[0];
  const float* Wg  = (const float*)d_in[1];
  const float* W1  = (const float*)d_in[2];
  const float* b1  = (const float*)d_in[3];
  const float* W2  = (const float*)d_in[4];
  const float* b2  = (const float*)d_in[5];
  const float* Ws1 = (const float*)d_in[6];
  const float* bs1 = (const float*)d_in[7];
  const float* Ws2 = (const float*)d_in[8];
  const float* bs2 = (const float*)d_in[9];

  // workspace layout (~276 MiB)
  char* ws = (char*)d_ws;
  size_t off = 0;
  auto alloc = [&](size_t bytes) -> char* {
    char* p = ws + off;
    off = (off + bytes + 255) & ~(size_t)255;
    return p;
  };
  int*   counts  = (int*)  alloc(NE * 4);
  int*   pad_off = (int*)  alloc((NE + 2) * 4);
  int*   cursor  = (int*)  alloc(NE * 4);
  int*   top_e   = (int*)  alloc((size_t)T_TOK * 2 * 4);
  float* top_w   = (float*)alloc((size_t)T_TOK * 2 * 4);
  int*   slot_of = (int*)  alloc((size_t)T_TOK * 2 * 4);
  u16*   Xb   = (u16*)alloc((size_t)T_TOK * DM * 2);         // 8 MB
  u16*   Xg   = (u16*)alloc((size_t)9216 * DM * 2);          // padded expert rows, 19 MB
  u16*   W1T  = (u16*)alloc((size_t)NE * DM * DF * 2);       // [e][DF][DM], 64 MB; dead after pass1
  u16*   W2T  = (u16*)alloc((size_t)NE * DM * DF * 2);       // [e][DM][DF], 64 MB
  u16*   Ws1T = (u16*)alloc((size_t)DM * DF * 2);            // [DF][DM], 8 MB
  u16*   Ws2T = (u16*)alloc((size_t)DM * DF * 2);            // [DM][DF], 8 MB
  u16*   H    = (u16*)alloc((size_t)MAXRB * 128 * DF * 2);   // 13312 rows, 104 MB
  u16*   Ytmp = W1T;   // 26 MB overlay: W1T fully rewritten every launch before pass1
  (void)ws_size; (void)in_sizes; (void)n_in;

  hipMemsetAsync(counts, 0, NE * 4, stream);

  cvt_x_kernel<<<(T_TOK * DM / 4 + 255) / 256, 256, 0, stream>>>(x, Xb, T_TOK * DM / 4);
  transpose_cvt9<<<dim3(DF / 64, DM / 64, NE + 1), 256, 0, stream>>>(W1, Ws1, W1T, Ws1T, DM, DF);
  transpose_cvt9<<<dim3(DM / 64, DF / 64, NE + 1), 256, 0, stream>>>(W2, Ws2, W2T, Ws2T, DF, DM);

  gating_kernel<<<T_TOK / 4, 256, 0, stream>>>(x, Wg, counts, top_e, top_w);
  offsets_kernel<<<1, 64, 0, stream>>>(counts, pad_off, cursor);
  scatter_kernel<<<T_TOK / 256, 256, 0, stream>>>(top_e, pad_off, cursor, slot_of);
  gather_x<<<2 * T_TOK, 256, 0, stream>>>(x, slot_of, Xg);

  // pass1: 32 col-blocks x 104 row-blocks = 3328 blocks (%8==0), ~13/CU
  ffn_gemm<1><<<(DF / 128) * MAXRB, 256, 0, stream>>>(
      Xb, Xg, H, W1T, Ws1T, b1, bs1, pad_off, Ytmp);
  // pass2: 8 col-blocks x 104 row-blocks = 832 blocks (%8==0), ~3/CU
  ffn_gemm<2><<<(DM / 128) * MAXRB, 256, 0, stream>>>(
      Xb, Xg, H, W2T, Ws2T, b2, bs2, pad_off, Ytmp);

  combine_kernel<<<(T_TOK * 128) / 256, 256, 0, stream>>>(
      Ytmp, slot_of, top_e, top_w, b2, bs2, pad_off, (float*)d_out);
}